// Round 4
// baseline (485.727 us; speedup 1.0000x reference)
//
#include <hip/hip_runtime.h>
#include <cstddef>
#include <cstdint>

namespace {

constexpr int kN = 32;
constexpr int kC = 512;
constexpr int kHW = 3136;   // 56*56
constexpr int kL = 64;
constexpr int kCT = 512;
constexpr int kTok = 561;   // CT + 49
constexpr int kKcat = 576;  // 561 padded to 18*32

typedef float fx4 __attribute__((ext_vector_type(4)));
typedef float f32x4 __attribute__((ext_vector_type(4)));
typedef short short8 __attribute__((ext_vector_type(8)));
typedef unsigned int u32x2 __attribute__((ext_vector_type(2)));
typedef unsigned int u32x4 __attribute__((ext_vector_type(4)));

// round-half-up f32->bf16, pack two into one u32 (low = a, high = b)
static __device__ inline unsigned pack_bf16(float a, float b) {
  unsigned ua = __builtin_bit_cast(unsigned, a) + 0x8000u;
  unsigned ub = __builtin_bit_cast(unsigned, b) + 0x8000u;
  return __builtin_amdgcn_perm(ub, ua, 0x07060302u);
}

// ---------------- weight prep ----------------
__global__ __launch_bounds__(256) void build_wcat_kernel(
    const float* __restrict__ w_tok, const float* __restrict__ w_val,
    float* __restrict__ wcat) {
  int idx = blockIdx.x * 256 + threadIdx.x;
  if (idx >= kCT * kKcat) return;
  int d = idx / kKcat;
  int c = idx - d * kKcat;
  float v = 0.f;
  if (c < kCT) {
    int g = c >> 5, k = c & 31;
    const float* wt = w_tok + (size_t)d * kTok + g * 32;
    const float* wv = w_val + g * 1024 + k;
    float s = 0.f;
#pragma unroll
    for (int dp = 0; dp < 32; ++dp) s += wt[dp] * wv[dp * 32];
    v = s;
  } else if (c < kTok) {
    v = w_tok[(size_t)d * kTok + c];
  }
  wcat[idx] = v;
}

__global__ __launch_bounds__(256) void build_cst_kernel(
    const float* __restrict__ w_tok, const float* __restrict__ b_val,
    const float* __restrict__ b_tok, float* __restrict__ cst) {
  int d = blockIdx.x * 256 + threadIdx.x;
  if (d >= kCT) return;
  float s = b_tok[d];
  for (int c = 0; c < kCT; ++c) s += w_tok[(size_t)d * kTok + c] * b_val[c];
  cst[d] = s;
}

// ---------------- K1: tcT[n][l][p] = (w_tc @ feat + b_tc)/sqrt(C), bf16 MFMA ----------------
// Also emits featB[n][c][p] (bf16 copy of feature) as a side product.
// block 256 thr (4 waves), tile 64 l x 256 p, BK=64 c; grid (13, N). p clamped.
__global__ __launch_bounds__(256) void tc_gemm_kernel(
    const float* __restrict__ feat, const float* __restrict__ w_tc,
    const float* __restrict__ b_tc, float* __restrict__ tcT,
    unsigned short* __restrict__ featB) {
  const int n = blockIdx.y;
  const int pb = blockIdx.x * 256;
  const int tid = threadIdx.x;
  const int wave = tid >> 6, lane = tid & 63;
  const int quad = lane >> 4, l16 = lane & 15;
  __shared__ unsigned short As[64][72];
  __shared__ unsigned short Bs[256][72];
  __shared__ float bsm[64];
  if (tid < 64) bsm[tid] = b_tc[tid];

  f32x4 acc[4][4];
#pragma unroll
  for (int i = 0; i < 4; ++i)
#pragma unroll
    for (int j = 0; j < 4; ++j) acc[i][j] = (f32x4){0.f, 0.f, 0.f, 0.f};

  const float* fb = feat + (size_t)n * kC * kHW;
  unsigned short* fBo = featB + (size_t)n * kC * kHW;
  const int al = tid & 63, akg = (tid >> 6) * 16;
  const int bc4 = (tid & 15) * 4, bpl0 = (tid >> 4) * 4;

  for (int c0 = 0; c0 < kC; c0 += 64) {
    // stage A = w_tc rows [l][c]
    const float* asrc = w_tc + (size_t)al * kC + c0 + akg;
#pragma unroll
    for (int u = 0; u < 4; ++u) {
      fx4 v = *(const fx4*)(asrc + u * 4);
      u32x2 w = {pack_bf16(v[0], v[1]), pack_bf16(v[2], v[3])};
      *(u32x2*)&As[al][akg + u * 4] = w;
    }
    // stage B = feature^T tile: Bs[p][c]; also write featB[c][p] bf16
#pragma unroll
    for (int pass = 0; pass < 4; ++pass) {
      int pl = bpl0 + pass * 64;
      int pe = pb + pl;
      pe = pe < 3132 ? pe : 3132;
      fx4 v0 = *(const fx4*)(fb + (size_t)(c0 + bc4 + 0) * kHW + pe);
      fx4 v1 = *(const fx4*)(fb + (size_t)(c0 + bc4 + 1) * kHW + pe);
      fx4 v2 = *(const fx4*)(fb + (size_t)(c0 + bc4 + 2) * kHW + pe);
      fx4 v3 = *(const fx4*)(fb + (size_t)(c0 + bc4 + 3) * kHW + pe);
      // featB rows (k-contiguous bf16 for m_gemm). Duplicate clamped writes
      // store identical data - benign.
      u32x2 r0 = {pack_bf16(v0[0], v0[1]), pack_bf16(v0[2], v0[3])};
      u32x2 r1 = {pack_bf16(v1[0], v1[1]), pack_bf16(v1[2], v1[3])};
      u32x2 r2 = {pack_bf16(v2[0], v2[1]), pack_bf16(v2[2], v2[3])};
      u32x2 r3 = {pack_bf16(v3[0], v3[1]), pack_bf16(v3[2], v3[3])};
      *(u32x2*)(fBo + (size_t)(c0 + bc4 + 0) * kHW + pe) = r0;
      *(u32x2*)(fBo + (size_t)(c0 + bc4 + 1) * kHW + pe) = r1;
      *(u32x2*)(fBo + (size_t)(c0 + bc4 + 2) * kHW + pe) = r2;
      *(u32x2*)(fBo + (size_t)(c0 + bc4 + 3) * kHW + pe) = r3;
#pragma unroll
      for (int j = 0; j < 4; ++j) {
        u32x2 w = {pack_bf16(v0[j], v1[j]), pack_bf16(v2[j], v3[j])};
        *(u32x2*)&Bs[pl + j][bc4] = w;
      }
    }
    __syncthreads();
#pragma unroll
    for (int ks = 0; ks < 2; ++ks) {
      short8 a[4], b[4];
#pragma unroll
      for (int i = 0; i < 4; ++i)
        a[i] = *(const short8*)&As[i * 16 + l16][ks * 32 + quad * 8];
#pragma unroll
      for (int j = 0; j < 4; ++j)
        b[j] = *(const short8*)&Bs[wave * 64 + j * 16 + l16][ks * 32 + quad * 8];
#pragma unroll
      for (int i = 0; i < 4; ++i)
#pragma unroll
        for (int j = 0; j < 4; ++j)
          acc[i][j] = __builtin_amdgcn_mfma_f32_16x16x32_bf16(a[i], b[j], acc[i][j], 0, 0, 0);
    }
    __syncthreads();
  }

  const float inv = 0.04419417382415922f;  // 1/sqrt(512)
  float* ob = tcT + (size_t)n * kL * kHW;
#pragma unroll
  for (int ti = 0; ti < 4; ++ti) {
#pragma unroll
    for (int tj = 0; tj < 4; ++tj) {
      int pg = pb + wave * 64 + tj * 16 + l16;
      if (pg < kHW) {
#pragma unroll
        for (int r = 0; r < 4; ++r) {
          int l = ti * 16 + quad * 4 + r;
          ob[(size_t)l * kHW + pg] = (acc[ti][tj][r] + bsm[l]) * inv;
        }
      }
    }
  }
}

// ---------------- K2: softmax stats, one wave per (n,l) row ----------------
__global__ __launch_bounds__(256) void softmax_stats_kernel(
    const float* __restrict__ tcT, float* __restrict__ mArr,
    float* __restrict__ invArr) {
  const int row = blockIdx.x * 4 + (threadIdx.x >> 6);
  const int lane = threadIdx.x & 63;
  const float* src = tcT + (size_t)row * kHW + lane * 4;
  fx4 x[13];
#pragma unroll
  for (int i = 0; i < 12; ++i) x[i] = *(const fx4*)(src + i * 256);
  if (lane < 16)
    x[12] = *(const fx4*)(src + 3072);
  else
    x[12] = (fx4){-1e30f, -1e30f, -1e30f, -1e30f};
  float m = -1e30f;
#pragma unroll
  for (int i = 0; i < 13; ++i)
    m = fmaxf(m, fmaxf(fmaxf(x[i][0], x[i][1]), fmaxf(x[i][2], x[i][3])));
#pragma unroll
  for (int off = 32; off >= 1; off >>= 1) m = fmaxf(m, __shfl_xor(m, off));
  float s = 0.f;
#pragma unroll
  for (int i = 0; i < 13; ++i) {
    s += __expf(x[i][0] - m) + __expf(x[i][1] - m) + __expf(x[i][2] - m) +
         __expf(x[i][3] - m);
  }
#pragma unroll
  for (int off = 32; off >= 1; off >>= 1) s += __shfl_xor(s, off);
  if (lane == 0) {
    mArr[row] = m;
    invArr[row] = 1.f / s;
  }
}

// ---------------- K3: part[s][n][l][c] = softmax(tcT) @ featB^T, bf16 MFMA ----------------
// block 256 thr, tile 64 l x 256 c, BK=64 p; grid (2, N, 7)
__global__ __launch_bounds__(256) void m_gemm_kernel(
    const unsigned short* __restrict__ featB, const float* __restrict__ tcT,
    const float* __restrict__ mArr, const float* __restrict__ invArr,
    float* __restrict__ part, int klen) {
  const int cb = blockIdx.x * 256;
  const int n = blockIdx.y;
  const int s = blockIdx.z;
  const int p0s = s * klen;
  const int tid = threadIdx.x;
  const int wave = tid >> 6, lane = tid & 63;
  const int quad = lane >> 4, l16 = lane & 15;
  __shared__ unsigned short As[64][72];
  __shared__ unsigned short Bs[256][72];

  const int al = tid & 63, akg = (tid >> 6) * 16;
  const float sm = mArr[n * 64 + al];
  const float si = invArr[n * 64 + al];

  f32x4 acc[4][4];
#pragma unroll
  for (int i = 0; i < 4; ++i)
#pragma unroll
    for (int j = 0; j < 4; ++j) acc[i][j] = (f32x4){0.f, 0.f, 0.f, 0.f};

  const float* tb = tcT + (size_t)(n * 64 + al) * kHW;
  const unsigned short* fBo = featB + (size_t)n * kC * kHW;
  const int bkg = (tid >> 6) * 16, bcr = tid & 63;

  for (int p0 = p0s; p0 < p0s + klen; p0 += 64) {
    // stage A = exp-normalized tcT rows [l][p]
#pragma unroll
    for (int u = 0; u < 4; ++u) {
      fx4 v = *(const fx4*)(tb + p0 + akg + u * 4);
      float e0 = __expf(v[0] - sm) * si;
      float e1 = __expf(v[1] - sm) * si;
      float e2 = __expf(v[2] - sm) * si;
      float e3 = __expf(v[3] - sm) * si;
      u32x2 w = {pack_bf16(e0, e1), pack_bf16(e2, e3)};
      *(u32x2*)&As[al][akg + u * 4] = w;
    }
    // stage B = featB rows [c][p] (already bf16, pure copy)
#pragma unroll
    for (int pass = 0; pass < 4; ++pass) {
      int c = cb + pass * 64 + bcr;
      const unsigned short* src = fBo + (size_t)c * kHW + p0 + bkg;
      u32x4 v0 = *(const u32x4*)src;
      u32x4 v1 = *(const u32x4*)(src + 8);
      *(u32x4*)&Bs[pass * 64 + bcr][bkg] = v0;
      *(u32x4*)&Bs[pass * 64 + bcr][bkg + 8] = v1;
    }
    __syncthreads();
#pragma unroll
    for (int ks = 0; ks < 2; ++ks) {
      short8 a[4], b[4];
#pragma unroll
      for (int i = 0; i < 4; ++i)
        a[i] = *(const short8*)&As[i * 16 + l16][ks * 32 + quad * 8];
#pragma unroll
      for (int j = 0; j < 4; ++j)
        b[j] = *(const short8*)&Bs[wave * 64 + j * 16 + l16][ks * 32 + quad * 8];
#pragma unroll
      for (int i = 0; i < 4; ++i)
#pragma unroll
        for (int j = 0; j < 4; ++j)
          acc[i][j] = __builtin_amdgcn_mfma_f32_16x16x32_bf16(a[i], b[j], acc[i][j], 0, 0, 0);
    }
    __syncthreads();
  }

  float* ob = part + (size_t)(s * kN + n) * kL * kCT;
#pragma unroll
  for (int ti = 0; ti < 4; ++ti) {
#pragma unroll
    for (int tj = 0; tj < 4; ++tj) {
      int cg = cb + wave * 64 + tj * 16 + l16;
#pragma unroll
      for (int r = 0; r < 4; ++r) {
        int l = ti * 16 + quad * 4 + r;
        ob[(size_t)l * kCT + cg] = acc[ti][tj][r];
      }
    }
  }
}

// ---------------- reduce: bcat[n][l][c] = sum_s part[s][n][l][c] ----------------
__global__ __launch_bounds__(256) void reduce_m_kernel(
    const float* __restrict__ part, float* __restrict__ bcat, int ksplit) {
  int i = blockIdx.x * 256 + threadIdx.x;
  if (i >= kN * kL * kCT) return;
  int n = i >> 15;
  int r = i & 32767;
  int l = r >> 9;
  int c = r & 511;
  float s = 0.f;
  for (int ss = 0; ss < ksplit; ++ss)
    s += part[(size_t)ss * kN * kL * kCT + i];
  bcat[(size_t)n * kL * kKcat + (size_t)l * kKcat + c] = s;
}

// ---------------- K4a: PosEncoder conv ----------------
__global__ __launch_bounds__(256) void pos_conv_kernel(
    const float* __restrict__ tcT, const float* __restrict__ mArr,
    const float* __restrict__ invArr, const float* __restrict__ w3,
    const float* __restrict__ b3, const float* __restrict__ w1,
    const float* __restrict__ b1, float* __restrict__ pcl) {
  int idx = blockIdx.x * 256 + threadIdx.x;
  if (idx >= kN * kL * 49) return;
  int n = idx / (kL * 49);
  int r = idx - n * (kL * 49);
  int lp = r / 49;
  int o = r - lp * 49;
  int y = o / 7, x = o - y * 7;
  const float* tb = tcT + (size_t)n * kL * kHW;
  const float* mB = mArr + n * 64;
  const float* iB = invArr + n * 64;
  float a = 0.f;
#pragma unroll
  for (int dy = 0; dy < 3; ++dy) {
    int i = 2 * y - 1 + dy;
    if (i < 0 || i >= 14) continue;
#pragma unroll
    for (int dx = 0; dx < 3; ++dx) {
      int j = 2 * x - 1 + dx;
      if (j < 0 || j >= 14) continue;
      int t = 224 * i + 4 * j;          // flat offset within image block
      int lsm = t & 63;                  // softmax channel
      int p = lp * 49 + (t >> 6);        // p-row in tcT
      float raw = tb[(size_t)lsm * kHW + p];
      a += w3[dy * 3 + dx] * (__expf(raw - mB[lsm]) * iB[lsm]);
    }
  }
  pcl[idx] = (a + b3[0]) * w1[0] + b1[0];
}

// ---------------- K4b: pos -> bcat[n][l][512+d], d<49 real, 49..63 zero pad ----------------
__global__ __launch_bounds__(256) void pos_out_kernel(
    const float* __restrict__ pcl, const float* __restrict__ wp,
    const float* __restrict__ bp, float* __restrict__ bcat) {
  const int n = blockIdx.x;
  __shared__ float t[64 * 49];
  for (int i = threadIdx.x; i < 64 * 49; i += 256)
    t[i] = pcl[(size_t)n * 64 * 49 + i];
  __syncthreads();
  for (int o = threadIdx.x; o < 64 * 64; o += 256) {
    int l = o >> 6, d = o & 63;
    float s = 0.f;
    if (d < 49) {
      s = bp[d];
#pragma unroll 7
      for (int q = 0; q < 49; ++q) s += wp[d * 49 + q] * t[l * 49 + q];
    }
    bcat[(size_t)n * kL * kKcat + (size_t)l * kKcat + kCT + d] = s;
  }
}

// ---------------- K5: out[n][d][l] = cst[d] + wcat[d,:] @ bcat[n][l,:], bf16 MFMA ----------------
// block 256 thr, tile 128 d x 64 l, BK=64; grid (4, N)
__global__ __launch_bounds__(256) void out_gemm_kernel(
    const float* __restrict__ wcat, const float* __restrict__ bcat,
    const float* __restrict__ cst, float* __restrict__ out) {
  const int db = blockIdx.x * 128;
  const int n = blockIdx.y;
  const int tid = threadIdx.x;
  const int wave = tid >> 6, lane = tid & 63;
  const int quad = lane >> 4, l16 = lane & 15;
  __shared__ unsigned short As[128][72];
  __shared__ unsigned short Bs[64][72];
  __shared__ float csm[128];
  if (tid < 128) csm[tid] = cst[db + tid];

  f32x4 acc[2][4];
#pragma unroll
  for (int i = 0; i < 2; ++i)
#pragma unroll
    for (int j = 0; j < 4; ++j) acc[i][j] = (f32x4){0.f, 0.f, 0.f, 0.f};

  const int ad = tid & 127, akg = (tid >> 7) * 32;
  const int bl = tid & 63, bkg = (tid >> 6) * 16;
  const float* ab = wcat + (size_t)(db + ad) * kKcat + akg;
  const float* bb = bcat + (size_t)n * kL * kKcat + (size_t)bl * kKcat + bkg;

  for (int k0 = 0; k0 < kKcat; k0 += 64) {
#pragma unroll
    for (int u = 0; u < 8; ++u) {
      fx4 v = *(const fx4*)(ab + k0 + u * 4);
      u32x2 w = {pack_bf16(v[0], v[1]), pack_bf16(v[2], v[3])};
      *(u32x2*)&As[ad][akg + u * 4] = w;
    }
#pragma unroll
    for (int u = 0; u < 4; ++u) {
      fx4 v = *(const fx4*)(bb + k0 + u * 4);
      u32x2 w = {pack_bf16(v[0], v[1]), pack_bf16(v[2], v[3])};
      *(u32x2*)&Bs[bl][bkg + u * 4] = w;
    }
    __syncthreads();
#pragma unroll
    for (int ks = 0; ks < 2; ++ks) {
      short8 a[2], b[4];
#pragma unroll
      for (int i = 0; i < 2; ++i)
        a[i] = *(const short8*)&As[wave * 32 + i * 16 + l16][ks * 32 + quad * 8];
#pragma unroll
      for (int j = 0; j < 4; ++j)
        b[j] = *(const short8*)&Bs[j * 16 + l16][ks * 32 + quad * 8];
#pragma unroll
      for (int i = 0; i < 2; ++i)
#pragma unroll
        for (int j = 0; j < 4; ++j)
          acc[i][j] = __builtin_amdgcn_mfma_f32_16x16x32_bf16(a[i], b[j], acc[i][j], 0, 0, 0);
    }
    __syncthreads();
  }

  float* ob = out + (size_t)n * kCT * kL;
#pragma unroll
  for (int ti = 0; ti < 2; ++ti) {
#pragma unroll
    for (int tj = 0; tj < 4; ++tj) {
      int lg = tj * 16 + l16;
#pragma unroll
      for (int r = 0; r < 4; ++r) {
        int dl = wave * 32 + ti * 16 + quad * 4 + r;
        ob[(size_t)(db + dl) * kL + lg] = acc[ti][tj][r] + csm[dl];
      }
    }
  }
}

}  // namespace

extern "C" void kernel_launch(void* const* d_in, const int* in_sizes, int n_in,
                              void* d_out, int out_size, void* d_ws,
                              size_t ws_size, hipStream_t stream) {
  (void)in_sizes; (void)n_in; (void)out_size;
  const float* feat  = (const float*)d_in[0];
  const float* w_tc  = (const float*)d_in[1];
  const float* b_tc  = (const float*)d_in[2];
  const float* w_val = (const float*)d_in[3];
  const float* b_val = (const float*)d_in[4];
  const float* w_ds3 = (const float*)d_in[5];
  const float* b_ds3 = (const float*)d_in[6];
  const float* w_ds1 = (const float*)d_in[7];
  const float* b_ds1 = (const float*)d_in[8];
  const float* w_pos = (const float*)d_in[9];
  const float* b_pos = (const float*)d_in[10];
  const float* w_tok = (const float*)d_in[11];
  const float* b_tok = (const float*)d_in[12];
  float* out = (float*)d_out;

  float* ws = (float*)d_ws;
  size_t off = 0;
  float* tcT = ws + off;    off += (size_t)kN * kL * kHW;    // 6,422,528
  float* bcat = ws + off;   off += (size_t)kN * kL * kKcat;  // 1,179,648
  float* wcat = ws + off;   off += (size_t)kCT * kKcat;      //   294,912
  float* cst = ws + off;    off += kCT;
  float* mArr = ws + off;   off += kN * 64;
  float* invArr = ws + off; off += kN * 64;
  float* pcl = ws + off;    off += (size_t)kN * kL * 49;
  unsigned short* featB = (unsigned short*)(ws + off);
  off += (size_t)kN * kC * kHW / 2;                          // 25,690,112 floats worth
  int ksplit = 7;
  if (ws_size < (off + (size_t)7 * kN * kL * kCT) * sizeof(float)) ksplit = 1;
  float* part = ws + off;

  build_wcat_kernel<<<(kCT * kKcat + 255) / 256, 256, 0, stream>>>(w_tok, w_val, wcat);
  build_cst_kernel<<<2, 256, 0, stream>>>(w_tok, b_val, b_tok, cst);
  tc_gemm_kernel<<<dim3(13, kN), 256, 0, stream>>>(feat, w_tc, b_tc, tcT, featB);
  softmax_stats_kernel<<<kN * kL / 4, 256, 0, stream>>>(tcT, mArr, invArr);
  m_gemm_kernel<<<dim3(2, kN, ksplit), 256, 0, stream>>>(
      featB, tcT, mArr, invArr, part, kHW / ksplit);
  reduce_m_kernel<<<(kN * kL * kCT + 255) / 256, 256, 0, stream>>>(part, bcat, ksplit);
  pos_conv_kernel<<<(kN * kL * 49 + 255) / 256, 256, 0, stream>>>(
      tcT, mArr, invArr, w_ds3, b_ds3, w_ds1, b_ds1, pcl);
  pos_out_kernel<<<kN, 256, 0, stream>>>(pcl, w_pos, b_pos, bcat);
  out_gemm_kernel<<<dim3(4, kN), 256, 0, stream>>>(wcat, bcat, cst, out);
}

// Round 5
// 464.040 us; speedup vs baseline: 1.0467x; 1.0467x over previous
//
#include <hip/hip_runtime.h>
#include <cstddef>
#include <cstdint>

namespace {

constexpr int kN = 32;
constexpr int kC = 512;
constexpr int kHW = 3136;   // 56*56
constexpr int kL = 64;
constexpr int kCT = 512;
constexpr int kTok = 561;   // CT + 49
constexpr int kKcat = 576;  // 561 padded to 18*32

typedef float fx4 __attribute__((ext_vector_type(4)));
typedef float f32x4 __attribute__((ext_vector_type(4)));
typedef short short8 __attribute__((ext_vector_type(8)));
typedef unsigned int u32x2 __attribute__((ext_vector_type(2)));

// round-half-up f32->bf16, pack two into one u32 (low = a, high = b)
static __device__ inline unsigned pack_bf16(float a, float b) {
  unsigned ua = __builtin_bit_cast(unsigned, a) + 0x8000u;
  unsigned ub = __builtin_bit_cast(unsigned, b) + 0x8000u;
  return __builtin_amdgcn_perm(ub, ua, 0x07060302u);
}

// ---------------- weight prep ----------------
__global__ __launch_bounds__(256) void build_wcat_kernel(
    const float* __restrict__ w_tok, const float* __restrict__ w_val,
    float* __restrict__ wcat) {
  int idx = blockIdx.x * 256 + threadIdx.x;
  if (idx >= kCT * kKcat) return;
  int d = idx / kKcat;
  int c = idx - d * kKcat;
  float v = 0.f;
  if (c < kCT) {
    int g = c >> 5, k = c & 31;
    const float* wt = w_tok + (size_t)d * kTok + g * 32;
    const float* wv = w_val + g * 1024 + k;
    float s = 0.f;
#pragma unroll
    for (int dp = 0; dp < 32; ++dp) s += wt[dp] * wv[dp * 32];
    v = s;
  } else if (c < kTok) {
    v = w_tok[(size_t)d * kTok + c];
  }
  wcat[idx] = v;
}

__global__ __launch_bounds__(256) void build_cst_kernel(
    const float* __restrict__ w_tok, const float* __restrict__ b_val,
    const float* __restrict__ b_tok, float* __restrict__ cst) {
  int d = blockIdx.x * 256 + threadIdx.x;
  if (d >= kCT) return;
  float s = b_tok[d];
  for (int c = 0; c < kCT; ++c) s += w_tok[(size_t)d * kTok + c] * b_val[c];
  cst[d] = s;
}

// ---------------- K1: tcT[n][l][p] = (w_tc @ feat + b_tc)/sqrt(C), bf16 MFMA ----------------
// block 256 thr (4 waves), tile 64 l x 128 p, BK=64 c; grid (25, N). p clamped.
__global__ __launch_bounds__(256) void tc_gemm_kernel(
    const float* __restrict__ feat, const float* __restrict__ w_tc,
    const float* __restrict__ b_tc, float* __restrict__ tcT) {
  const int n = blockIdx.y;
  const int pb = blockIdx.x * 128;
  const int tid = threadIdx.x;
  const int wave = tid >> 6, lane = tid & 63;
  const int quad = lane >> 4, l16 = lane & 15;
  __shared__ unsigned short As[64][72];
  __shared__ unsigned short Bs[128][72];
  __shared__ float bsm[64];
  if (tid < 64) bsm[tid] = b_tc[tid];

  f32x4 acc[4][2];
#pragma unroll
  for (int i = 0; i < 4; ++i)
#pragma unroll
    for (int j = 0; j < 2; ++j) acc[i][j] = (f32x4){0.f, 0.f, 0.f, 0.f};

  const float* fb = feat + (size_t)n * kC * kHW;
  const int al = tid & 63, akg = (tid >> 6) * 16;
  const int bc4 = (tid & 15) * 4, bpl0 = (tid >> 4) * 4;

  for (int c0 = 0; c0 < kC; c0 += 64) {
    // stage A = w_tc rows [l][c]
    const float* asrc = w_tc + (size_t)al * kC + c0 + akg;
#pragma unroll
    for (int u = 0; u < 4; ++u) {
      fx4 v = *(const fx4*)(asrc + u * 4);
      u32x2 w = {pack_bf16(v[0], v[1]), pack_bf16(v[2], v[3])};
      *(u32x2*)&As[al][akg + u * 4] = w;
    }
    // stage B = feature^T tile: Bs[p][c], transpose 4x4 in regs
#pragma unroll
    for (int pass = 0; pass < 2; ++pass) {
      int pl = bpl0 + pass * 64;
      int pe = pb + pl;
      pe = pe < 3132 ? pe : 3132;
      fx4 v0 = *(const fx4*)(fb + (size_t)(c0 + bc4 + 0) * kHW + pe);
      fx4 v1 = *(const fx4*)(fb + (size_t)(c0 + bc4 + 1) * kHW + pe);
      fx4 v2 = *(const fx4*)(fb + (size_t)(c0 + bc4 + 2) * kHW + pe);
      fx4 v3 = *(const fx4*)(fb + (size_t)(c0 + bc4 + 3) * kHW + pe);
#pragma unroll
      for (int j = 0; j < 4; ++j) {
        u32x2 w = {pack_bf16(v0[j], v1[j]), pack_bf16(v2[j], v3[j])};
        *(u32x2*)&Bs[pl + j][bc4] = w;
      }
    }
    __syncthreads();
#pragma unroll
    for (int ks = 0; ks < 2; ++ks) {
      short8 a[4], b[2];
#pragma unroll
      for (int i = 0; i < 4; ++i)
        a[i] = *(const short8*)&As[i * 16 + l16][ks * 32 + quad * 8];
#pragma unroll
      for (int j = 0; j < 2; ++j)
        b[j] = *(const short8*)&Bs[wave * 32 + j * 16 + l16][ks * 32 + quad * 8];
#pragma unroll
      for (int i = 0; i < 4; ++i)
#pragma unroll
        for (int j = 0; j < 2; ++j)
          acc[i][j] = __builtin_amdgcn_mfma_f32_16x16x32_bf16(a[i], b[j], acc[i][j], 0, 0, 0);
    }
    __syncthreads();
  }

  const float inv = 0.04419417382415922f;  // 1/sqrt(512)
  float* ob = tcT + (size_t)n * kL * kHW;
#pragma unroll
  for (int ti = 0; ti < 4; ++ti) {
#pragma unroll
    for (int tj = 0; tj < 2; ++tj) {
      int pg = pb + wave * 32 + tj * 16 + l16;
      if (pg < kHW) {
#pragma unroll
        for (int r = 0; r < 4; ++r) {
          int l = ti * 16 + quad * 4 + r;
          ob[(size_t)l * kHW + pg] = (acc[ti][tj][r] + bsm[l]) * inv;
        }
      }
    }
  }
}

// ---------------- K2: softmax stats, one wave per (n,l) row ----------------
__global__ __launch_bounds__(256) void softmax_stats_kernel(
    const float* __restrict__ tcT, float* __restrict__ mArr,
    float* __restrict__ invArr) {
  const int row = blockIdx.x * 4 + (threadIdx.x >> 6);
  const int lane = threadIdx.x & 63;
  const float* src = tcT + (size_t)row * kHW + lane * 4;
  fx4 x[13];
#pragma unroll
  for (int i = 0; i < 12; ++i) x[i] = *(const fx4*)(src + i * 256);
  if (lane < 16)
    x[12] = *(const fx4*)(src + 3072);
  else
    x[12] = (fx4){-1e30f, -1e30f, -1e30f, -1e30f};
  float m = -1e30f;
#pragma unroll
  for (int i = 0; i < 13; ++i)
    m = fmaxf(m, fmaxf(fmaxf(x[i][0], x[i][1]), fmaxf(x[i][2], x[i][3])));
#pragma unroll
  for (int off = 32; off >= 1; off >>= 1) m = fmaxf(m, __shfl_xor(m, off));
  float s = 0.f;
#pragma unroll
  for (int i = 0; i < 13; ++i) {
    s += __expf(x[i][0] - m) + __expf(x[i][1] - m) + __expf(x[i][2] - m) +
         __expf(x[i][3] - m);
  }
#pragma unroll
  for (int off = 32; off >= 1; off >>= 1) s += __shfl_xor(s, off);
  if (lane == 0) {
    mArr[row] = m;
    invArr[row] = 1.f / s;
  }
}

// ---------------- K3: part[s][n][l][c] = softmax(tcT) @ feat^T, bf16 MFMA ----------------
// block 256 thr, tile 64 l x 128 c, BK=64 p; grid (4, N, 7)
__global__ __launch_bounds__(256) void m_gemm_kernel(
    const float* __restrict__ feat, const float* __restrict__ tcT,
    const float* __restrict__ mArr, const float* __restrict__ invArr,
    float* __restrict__ part, int klen) {
  const int cb = blockIdx.x * 128;
  const int n = blockIdx.y;
  const int s = blockIdx.z;
  const int p0s = s * klen;
  const int tid = threadIdx.x;
  const int wave = tid >> 6, lane = tid & 63;
  const int quad = lane >> 4, l16 = lane & 15;
  __shared__ unsigned short As[64][72];
  __shared__ unsigned short Bs[128][72];

  const int al = tid & 63, akg = (tid >> 6) * 16;
  const float sm = mArr[n * 64 + al];
  const float si = invArr[n * 64 + al];

  f32x4 acc[4][2];
#pragma unroll
  for (int i = 0; i < 4; ++i)
#pragma unroll
    for (int j = 0; j < 2; ++j) acc[i][j] = (f32x4){0.f, 0.f, 0.f, 0.f};

  const float* tb = tcT + (size_t)(n * 64 + al) * kHW;
  const float* fb = feat + (size_t)n * kC * kHW;
  const int bkg = (tid >> 6) * 16, bcr = tid & 63;

  for (int p0 = p0s; p0 < p0s + klen; p0 += 64) {
    // stage A = exp-normalized tcT rows [l][p]
#pragma unroll
    for (int u = 0; u < 4; ++u) {
      fx4 v = *(const fx4*)(tb + p0 + akg + u * 4);
      float e0 = __expf(v[0] - sm) * si;
      float e1 = __expf(v[1] - sm) * si;
      float e2 = __expf(v[2] - sm) * si;
      float e3 = __expf(v[3] - sm) * si;
      u32x2 w = {pack_bf16(e0, e1), pack_bf16(e2, e3)};
      *(u32x2*)&As[al][akg + u * 4] = w;
    }
    // stage B = feature rows [c][p] (native layout, coalesced 16B loads)
#pragma unroll
    for (int pass = 0; pass < 2; ++pass) {
      int c = cb + pass * 64 + bcr;
      const float* src = fb + (size_t)c * kHW + p0 + bkg;
#pragma unroll
      for (int u = 0; u < 4; ++u) {
        fx4 v = *(const fx4*)(src + u * 4);
        u32x2 w = {pack_bf16(v[0], v[1]), pack_bf16(v[2], v[3])};
        *(u32x2*)&Bs[pass * 64 + bcr][bkg + u * 4] = w;
      }
    }
    __syncthreads();
#pragma unroll
    for (int ks = 0; ks < 2; ++ks) {
      short8 a[4], b[2];
#pragma unroll
      for (int i = 0; i < 4; ++i)
        a[i] = *(const short8*)&As[i * 16 + l16][ks * 32 + quad * 8];
#pragma unroll
      for (int j = 0; j < 2; ++j)
        b[j] = *(const short8*)&Bs[wave * 32 + j * 16 + l16][ks * 32 + quad * 8];
#pragma unroll
      for (int i = 0; i < 4; ++i)
#pragma unroll
        for (int j = 0; j < 2; ++j)
          acc[i][j] = __builtin_amdgcn_mfma_f32_16x16x32_bf16(a[i], b[j], acc[i][j], 0, 0, 0);
    }
    __syncthreads();
  }

  float* ob = part + (size_t)(s * kN + n) * kL * kCT;
#pragma unroll
  for (int ti = 0; ti < 4; ++ti) {
#pragma unroll
    for (int tj = 0; tj < 2; ++tj) {
      int cg = cb + wave * 32 + tj * 16 + l16;
#pragma unroll
      for (int r = 0; r < 4; ++r) {
        int l = ti * 16 + quad * 4 + r;
        ob[(size_t)l * kCT + cg] = acc[ti][tj][r];
      }
    }
  }
}

// ---------------- reduce: bcat[n][l][c] = sum_s part[s][n][l][c] ----------------
__global__ __launch_bounds__(256) void reduce_m_kernel(
    const float* __restrict__ part, float* __restrict__ bcat, int ksplit) {
  int i = blockIdx.x * 256 + threadIdx.x;
  if (i >= kN * kL * kCT) return;
  int n = i >> 15;
  int r = i & 32767;
  int l = r >> 9;
  int c = r & 511;
  float s = 0.f;
  for (int ss = 0; ss < ksplit; ++ss)
    s += part[(size_t)ss * kN * kL * kCT + i];
  bcat[(size_t)n * kL * kKcat + (size_t)l * kKcat + c] = s;
}

// ---------------- K4a: PosEncoder conv ----------------
__global__ __launch_bounds__(256) void pos_conv_kernel(
    const float* __restrict__ tcT, const float* __restrict__ mArr,
    const float* __restrict__ invArr, const float* __restrict__ w3,
    const float* __restrict__ b3, const float* __restrict__ w1,
    const float* __restrict__ b1, float* __restrict__ pcl) {
  int idx = blockIdx.x * 256 + threadIdx.x;
  if (idx >= kN * kL * 49) return;
  int n = idx / (kL * 49);
  int r = idx - n * (kL * 49);
  int lp = r / 49;
  int o = r - lp * 49;
  int y = o / 7, x = o - y * 7;
  const float* tb = tcT + (size_t)n * kL * kHW;
  const float* mB = mArr + n * 64;
  const float* iB = invArr + n * 64;
  float a = 0.f;
#pragma unroll
  for (int dy = 0; dy < 3; ++dy) {
    int i = 2 * y - 1 + dy;
    if (i < 0 || i >= 14) continue;
#pragma unroll
    for (int dx = 0; dx < 3; ++dx) {
      int j = 2 * x - 1 + dx;
      if (j < 0 || j >= 14) continue;
      int t = 224 * i + 4 * j;          // flat offset within image block
      int lsm = t & 63;                  // softmax channel
      int p = lp * 49 + (t >> 6);        // p-row in tcT
      float raw = tb[(size_t)lsm * kHW + p];
      a += w3[dy * 3 + dx] * (__expf(raw - mB[lsm]) * iB[lsm]);
    }
  }
  pcl[idx] = (a + b3[0]) * w1[0] + b1[0];
}

// ---------------- K4b: pos -> bcat[n][l][512+d], d<49 real, 49..63 zero pad ----------------
__global__ __launch_bounds__(256) void pos_out_kernel(
    const float* __restrict__ pcl, const float* __restrict__ wp,
    const float* __restrict__ bp, float* __restrict__ bcat) {
  const int n = blockIdx.x;
  __shared__ float t[64 * 49];
  for (int i = threadIdx.x; i < 64 * 49; i += 256)
    t[i] = pcl[(size_t)n * 64 * 49 + i];
  __syncthreads();
  for (int o = threadIdx.x; o < 64 * 64; o += 256) {
    int l = o >> 6, d = o & 63;
    float s = 0.f;
    if (d < 49) {
      s = bp[d];
#pragma unroll 7
      for (int q = 0; q < 49; ++q) s += wp[d * 49 + q] * t[l * 49 + q];
    }
    bcat[(size_t)n * kL * kKcat + (size_t)l * kKcat + kCT + d] = s;
  }
}

// ---------------- K5: out[n][d][l] = cst[d] + wcat[d,:] @ bcat[n][l,:], bf16 MFMA ----------------
// block 256 thr, tile 128 d x 64 l, BK=64; grid (4, N)
__global__ __launch_bounds__(256) void out_gemm_kernel(
    const float* __restrict__ wcat, const float* __restrict__ bcat,
    const float* __restrict__ cst, float* __restrict__ out) {
  const int db = blockIdx.x * 128;
  const int n = blockIdx.y;
  const int tid = threadIdx.x;
  const int wave = tid >> 6, lane = tid & 63;
  const int quad = lane >> 4, l16 = lane & 15;
  __shared__ unsigned short As[128][72];
  __shared__ unsigned short Bs[64][72];
  __shared__ float csm[128];
  if (tid < 128) csm[tid] = cst[db + tid];

  f32x4 acc[2][4];
#pragma unroll
  for (int i = 0; i < 2; ++i)
#pragma unroll
    for (int j = 0; j < 4; ++j) acc[i][j] = (f32x4){0.f, 0.f, 0.f, 0.f};

  const int ad = tid & 127, akg = (tid >> 7) * 32;
  const int bl = tid & 63, bkg = (tid >> 6) * 16;
  const float* ab = wcat + (size_t)(db + ad) * kKcat + akg;
  const float* bb = bcat + (size_t)n * kL * kKcat + (size_t)bl * kKcat + bkg;

  for (int k0 = 0; k0 < kKcat; k0 += 64) {
#pragma unroll
    for (int u = 0; u < 8; ++u) {
      fx4 v = *(const fx4*)(ab + k0 + u * 4);
      u32x2 w = {pack_bf16(v[0], v[1]), pack_bf16(v[2], v[3])};
      *(u32x2*)&As[ad][akg + u * 4] = w;
    }
#pragma unroll
    for (int u = 0; u < 4; ++u) {
      fx4 v = *(const fx4*)(bb + k0 + u * 4);
      u32x2 w = {pack_bf16(v[0], v[1]), pack_bf16(v[2], v[3])};
      *(u32x2*)&Bs[bl][bkg + u * 4] = w;
    }
    __syncthreads();
#pragma unroll
    for (int ks = 0; ks < 2; ++ks) {
      short8 a[2], b[4];
#pragma unroll
      for (int i = 0; i < 2; ++i)
        a[i] = *(const short8*)&As[wave * 32 + i * 16 + l16][ks * 32 + quad * 8];
#pragma unroll
      for (int j = 0; j < 4; ++j)
        b[j] = *(const short8*)&Bs[j * 16 + l16][ks * 32 + quad * 8];
#pragma unroll
      for (int i = 0; i < 2; ++i)
#pragma unroll
        for (int j = 0; j < 4; ++j)
          acc[i][j] = __builtin_amdgcn_mfma_f32_16x16x32_bf16(a[i], b[j], acc[i][j], 0, 0, 0);
    }
    __syncthreads();
  }

  float* ob = out + (size_t)n * kCT * kL;
#pragma unroll
  for (int ti = 0; ti < 2; ++ti) {
#pragma unroll
    for (int tj = 0; tj < 4; ++tj) {
      int lg = tj * 16 + l16;
#pragma unroll
      for (int r = 0; r < 4; ++r) {
        int dl = wave * 32 + ti * 16 + quad * 4 + r;
        ob[(size_t)(db + dl) * kL + lg] = acc[ti][tj][r] + csm[dl];
      }
    }
  }
}

}  // namespace

extern "C" void kernel_launch(void* const* d_in, const int* in_sizes, int n_in,
                              void* d_out, int out_size, void* d_ws,
                              size_t ws_size, hipStream_t stream) {
  (void)in_sizes; (void)n_in; (void)out_size;
  const float* feat  = (const float*)d_in[0];
  const float* w_tc  = (const float*)d_in[1];
  const float* b_tc  = (const float*)d_in[2];
  const float* w_val = (const float*)d_in[3];
  const float* b_val = (const float*)d_in[4];
  const float* w_ds3 = (const float*)d_in[5];
  const float* b_ds3 = (const float*)d_in[6];
  const float* w_ds1 = (const float*)d_in[7];
  const float* b_ds1 = (const float*)d_in[8];
  const float* w_pos = (const float*)d_in[9];
  const float* b_pos = (const float*)d_in[10];
  const float* w_tok = (const float*)d_in[11];
  const float* b_tok = (const float*)d_in[12];
  float* out = (float*)d_out;

  float* ws = (float*)d_ws;
  size_t off = 0;
  float* tcT = ws + off;    off += (size_t)kN * kL * kHW;    // 6,422,528
  float* bcat = ws + off;   off += (size_t)kN * kL * kKcat;  // 1,179,648
  float* wcat = ws + off;   off += (size_t)kCT * kKcat;      //   294,912
  float* cst = ws + off;    off += kCT;
  float* mArr = ws + off;   off += kN * 64;
  float* invArr = ws + off; off += kN * 64;
  float* pcl = ws + off;    off += (size_t)kN * kL * 49;
  int ksplit = 7;
  if (ws_size < (off + (size_t)7 * kN * kL * kCT) * sizeof(float)) ksplit = 1;
  float* part = ws + off;

  build_wcat_kernel<<<(kCT * kKcat + 255) / 256, 256, 0, stream>>>(w_tok, w_val, wcat);
  build_cst_kernel<<<2, 256, 0, stream>>>(w_tok, b_val, b_tok, cst);
  tc_gemm_kernel<<<dim3(25, kN), 256, 0, stream>>>(feat, w_tc, b_tc, tcT);
  softmax_stats_kernel<<<kN * kL / 4, 256, 0, stream>>>(tcT, mArr, invArr);
  m_gemm_kernel<<<dim3(4, kN, ksplit), 256, 0, stream>>>(
      feat, tcT, mArr, invArr, part, kHW / ksplit);
  reduce_m_kernel<<<(kN * kL * kCT + 255) / 256, 256, 0, stream>>>(part, bcat, ksplit);
  pos_conv_kernel<<<(kN * kL * 49 + 255) / 256, 256, 0, stream>>>(
      tcT, mArr, invArr, w_ds3, b_ds3, w_ds1, b_ds1, pcl);
  pos_out_kernel<<<kN, 256, 0, stream>>>(pcl, w_pos, b_pos, bcat);
  out_gemm_kernel<<<dim3(4, kN), 256, 0, stream>>>(wcat, bcat, cst, out);
}